// Round 18
// baseline (336.171 us; speedup 1.0000x reference)
//
#include <hip/hip_runtime.h>
#include <hip/hip_bf16.h>

#define IN_DIM 768
#define HID 256
#define OUT_DIM 128
#define NHEAD 8
#define NREL 6
#define RD 64

typedef unsigned short ushort_t;
typedef float f32x4 __attribute__((ext_vector_type(4)));
typedef __bf16 bf16x8 __attribute__((ext_vector_type(8)));
typedef unsigned short u16x8 __attribute__((ext_vector_type(8)));
typedef unsigned short u16x4 __attribute__((ext_vector_type(4)));
typedef unsigned short u16x2 __attribute__((ext_vector_type(2)));

typedef const __attribute__((address_space(1))) void* gptr_t;
typedef __attribute__((address_space(3))) void* lptr_t;

static __device__ __forceinline__ float leaky(float x) { return x > 0.f ? x : 0.2f * x; }

static __device__ __forceinline__ ushort_t f2bf(float f) {
    union { __hip_bfloat16 h; ushort_t u; } c;
    c.h = __float2bfloat16(f);
    return c.u;
}

static __device__ __forceinline__ float b2f(ushort_t u) {
    union { unsigned int i; float f; } c;
    c.i = ((unsigned int)u) << 16;
    return c.f;
}

// ---------------- CSR build ----------------
__global__ void count_kernel(const int* __restrict__ dst0, int* __restrict__ deg, int E) {
    int e = blockIdx.x * blockDim.x + threadIdx.x;
    if (e >= E) return;
    atomicAdd(&deg[dst0[e]], 1);
}

// per-1024-chunk sums
__global__ void __launch_bounds__(256) scanA(const int* __restrict__ deg,
                                             int* __restrict__ bsum, int n) {
    __shared__ int sh[4];
    int b = blockIdx.x, t = threadIdx.x;
    int s = 0;
#pragma unroll
    for (int j = 0; j < 4; j++) {
        int idx = b * 1024 + t * 4 + j;
        if (idx < n) s += deg[idx];
    }
    for (int o = 32; o > 0; o >>= 1) s += __shfl_xor(s, o, 64);
    if ((t & 63) == 0) sh[t >> 6] = s;
    __syncthreads();
    if (t == 0) bsum[b] = sh[0] + sh[1] + sh[2] + sh[3];
}

// expand: each block serially scans the <=nb chunk sums for its base
__global__ void __launch_bounds__(256) scanC(const int* __restrict__ deg,
                                             const int* __restrict__ bsum,
                                             int* __restrict__ rowptr, int n, int nb) {
    __shared__ int sh[256];
    int b = blockIdx.x, t = threadIdx.x;
    int bb = 0;
    for (int k = 0; k < b; k++) bb += bsum[k];
    if (b == 0 && t == 0) {
        int tot = 0;
        for (int k = 0; k < nb; k++) tot += bsum[k];
        rowptr[n] = tot;
    }
    int base = b * 1024;
    int loc[4];
    int run = 0;
#pragma unroll
    for (int j = 0; j < 4; j++) {
        int idx = base + t * 4 + j;
        int d = (idx < n) ? deg[idx] : 0;
        loc[j] = run;
        run += d;
    }
    int tot = run;
    sh[t] = run;
    __syncthreads();
    for (int o = 1; o < 256; o <<= 1) {
        int add = (t >= o) ? sh[t - o] : 0;
        __syncthreads();
        sh[t] += add;
        __syncthreads();
    }
    int texcl = sh[t] - tot;
#pragma unroll
    for (int j = 0; j < 4; j++) {
        int idx = base + t * 4 + j;
        if (idx < n) rowptr[idx] = bb + texcl + loc[j];
    }
}

// packs src | (type<<24) into one word
__global__ void scatter_kernel(const int* __restrict__ src0, const int* __restrict__ dst0,
                               const int* __restrict__ ety, const int* __restrict__ rowptr,
                               int* __restrict__ fill, int* __restrict__ src_pk, int E) {
    int e = blockIdx.x * blockDim.x + threadIdx.x;
    if (e >= E) return;
    int d = dst0[e];
    int pos = rowptr[d] + atomicAdd(&fill[d], 1);
    src_pk[pos] = src0[e] | (ety[e] << 24);
}

// W1 transpose+cvt, W2 transpose+cvt, and rel_alpha — ONE launch
__global__ void prep_all(const float* __restrict__ W1, const float* __restrict__ W2,
                         const float* __restrict__ rel_emb, const float* __restrict__ We1,
                         const float* __restrict__ att_e1,
                         ushort_t* __restrict__ W1t, ushort_t* __restrict__ W2t,
                         float* __restrict__ rel_alpha) {
    int i = blockIdx.x * 256 + threadIdx.x;
    if (i < IN_DIM * HID) {
        int k = i / HID, n = i % HID;
        W1t[n * IN_DIM + k] = f2bf(W1[i]);
    } else if (i < IN_DIM * HID + HID * OUT_DIM) {
        int j = i - IN_DIM * HID;
        int k = j / OUT_DIM, n = j % OUT_DIM;
        W2t[n * HID + k] = f2bf(W2[j]);
    } else {
        int t = i - (IN_DIM * HID + HID * OUT_DIM);
        if (t < NREL * NHEAD) {
            int r = t / NHEAD, h = t % NHEAD;
            float acc = 0.f;
            for (int c = 0; c < HID / NHEAD; c++) {
                float v = 0.f;
                for (int k = 0; k < RD; k++) v += rel_emb[r * RD + k] * We1[k * HID + h * 32 + c];
                acc += v * att_e1[h * 32 + c];
            }
            rel_alpha[r * NHEAD + h] = acc;
        }
    }
}

// ------- gemm1: 64x128 tile, BK=32 single-buffer -> LDS 16KB -> ~6 blocks/CU (whole
// grid co-resident, ~24 waves/CU). Same staging/swizzle discipline as R17:
// A (8x16B chunks/row) key=row&7; B (4x16B chunks/row) key=(row>>1)&3 -> 2-way max.
__global__ void __launch_bounds__(256) gemm_f32a(const float* __restrict__ Af,
                                                 const ushort_t* __restrict__ Bt,
                                                 ushort_t* __restrict__ C,
                                                 int K, int Nout, int NBlk,
                                                 const float* __restrict__ att_s,
                                                 const float* __restrict__ att_d,
                                                 float* __restrict__ als,
                                                 float* __restrict__ ald, int N) {
    __shared__ float sAf[64 * 32];
    __shared__ ushort_t sB[128 * 32];
    int T = gridDim.x;
    int p = blockIdx.x;
    int q8 = T >> 3, rr8 = T & 7, xc = p & 7, jj0 = p >> 3;
    int l = (xc < rr8 ? xc * (q8 + 1) : rr8 * (q8 + 1) + (xc - rr8) * q8) + jj0;
    int m0 = (l / NBlk) * 64;
    int n0 = (l % NBlk) * 128;
    int t = threadIdx.x;
    int w = t >> 6, ln = t & 63;
    int wm = (w >> 1) * 32, wn = (w & 1) * 64;

    // A staging: 2 instr/wave; instr i: rows w*16+i*8+(ln>>3), chunk (ln&7)^(ln>>3)
    const float* agp[2];
#pragma unroll
    for (int i = 0; i < 2; i++) {
        int rl = w * 16 + i * 8 + (ln >> 3);
        int rg = min(m0 + rl, N - 1);  // clamp: tail-row outputs never consumed
        int cc = (ln & 7) ^ (ln >> 3);
        agp[i] = Af + (size_t)rg * K + (cc << 2);
    }
    // B staging: 2 instr/wave; rows w*32+i*16+(ln>>2), chunk (ln&3)^((ln>>3)&3)
    const ushort_t* bgp[2];
#pragma unroll
    for (int i = 0; i < 2; i++) {
        int rl = w * 32 + i * 16 + (ln >> 2);
        int cc = (ln & 3) ^ ((ln >> 3) & 3);
        bgp[i] = Bt + (size_t)(n0 + rl) * K + (cc << 3);
    }

    f32x4 acc[2][4] = {};

    for (int k0 = 0; k0 < K; k0 += 32) {
#pragma unroll
        for (int i = 0; i < 2; i++)
            __builtin_amdgcn_global_load_lds((gptr_t)(const void*)(agp[i] + k0),
                                             (lptr_t)(void*)(&sAf[(w * 16 + i * 8) * 32]),
                                             16, 0, 0);
#pragma unroll
        for (int i = 0; i < 2; i++)
            __builtin_amdgcn_global_load_lds((gptr_t)(const void*)(bgp[i] + k0),
                                             (lptr_t)(void*)(&sB[(w * 32 + i * 16) * 32]),
                                             16, 0, 0);
        __syncthreads();
        {
            bf16x8 af[2], bfr[4];
            int q = ln >> 4;  // 0..3
#pragma unroll
            for (int m = 0; m < 2; m++) {
                int r = wm + m * 16 + (ln & 15);
                int key = ln & 7;  // r & 7 (wm mult of 32, m*16 mult of 16... low-3 bits from ln&15)
                const f32x4* rowp = reinterpret_cast<const f32x4*>(&sAf[r * 32]);
                f32x4 lo = rowp[(2 * q) ^ key];
                f32x4 hi = rowp[(2 * q + 1) ^ key];
                union { u16x8 u; bf16x8 b; } cv;
                cv.u[0] = f2bf(lo[0]); cv.u[1] = f2bf(lo[1]);
                cv.u[2] = f2bf(lo[2]); cv.u[3] = f2bf(lo[3]);
                cv.u[4] = f2bf(hi[0]); cv.u[5] = f2bf(hi[1]);
                cv.u[6] = f2bf(hi[2]); cv.u[7] = f2bf(hi[3]);
                af[m] = cv.b;
            }
#pragma unroll
            for (int n = 0; n < 4; n++) {
                int r = wn + n * 16 + (ln & 15);
                int key = (ln >> 1) & 3;  // (r>>1)&3
                bfr[n] = *reinterpret_cast<const bf16x8*>(&sB[r * 32 + ((q ^ key) << 3)]);
            }
#pragma unroll
            for (int m = 0; m < 2; m++)
#pragma unroll
                for (int n = 0; n < 4; n++)
                    acc[m][n] = __builtin_amdgcn_mfma_f32_16x16x32_bf16(af[m], bfr[n], acc[m][n], 0, 0, 0);
        }
        __syncthreads();
    }

    int cc = ln & 15, qq = ln >> 4;
#pragma unroll
    for (int m = 0; m < 2; m++) {
#pragma unroll
        for (int rr = 0; rr < 4; rr++) {
            int row = m0 + wm + m * 16 + qq * 4 + rr;
#pragma unroll
            for (int n = 0; n < 4; n++)
                C[(size_t)row * Nout + n0 + wn + n * 16 + cc] = f2bf(acc[m][n][rr]);
        }
    }

    float as_[4], ad_[4];
#pragma unroll
    for (int n = 0; n < 4; n++) {
        int col = n0 + wn + n * 16 + cc;
        as_[n] = att_s[col];
        ad_[n] = att_d[col];
    }
    int hbase = (n0 + wn) >> 5;  // wave-exclusive head pair (rows split by w>>1)
#pragma unroll
    for (int m = 0; m < 2; m++) {
#pragma unroll
        for (int rr = 0; rr < 4; rr++) {
            int row = m0 + wm + m * 16 + qq * 4 + rr;
            float ps0 = acc[m][0][rr] * as_[0] + acc[m][1][rr] * as_[1];
            float ps1 = acc[m][2][rr] * as_[2] + acc[m][3][rr] * as_[3];
            float pd0 = acc[m][0][rr] * ad_[0] + acc[m][1][rr] * ad_[1];
            float pd1 = acc[m][2][rr] * ad_[2] + acc[m][3][rr] * ad_[3];
#pragma unroll
            for (int o = 1; o < 16; o <<= 1) {
                ps0 += __shfl_xor(ps0, o, 64);
                ps1 += __shfl_xor(ps1, o, 64);
                pd0 += __shfl_xor(pd0, o, 64);
                pd1 += __shfl_xor(pd1, o, 64);
            }
            if (cc == 0 && row < N) {
                als[row * NHEAD + hbase] = ps0;
                als[row * NHEAD + hbase + 1] = ps1;
                ald[row * NHEAD + hbase] = pd0;
                ald[row * NHEAD + hbase + 1] = pd1;
            }
        }
    }
}

// ------- gemm2 (bf16 A): BK=32 2-phase dbuf, AMODE-2 epilogue (unchanged) -------
__global__ void __launch_bounds__(256) gemm_lds2(const ushort_t* __restrict__ A,
                                                 const ushort_t* __restrict__ Bt,
                                                 ushort_t* __restrict__ C,
                                                 int K, int Nout, int NBlk,
                                                 const float* __restrict__ att_s,
                                                 const float* __restrict__ att_d,
                                                 float* __restrict__ als,
                                                 float* __restrict__ ald, int N) {
    __shared__ ushort_t sA[2][128 * 32];
    __shared__ ushort_t sB[2][128 * 32];
    int T = gridDim.x;
    int p = blockIdx.x;
    int q8 = T >> 3, rr8 = T & 7, xc = p & 7, j = p >> 3;
    int l = (xc < rr8 ? xc * (q8 + 1) : rr8 * (q8 + 1) + (xc - rr8) * q8) + j;
    int m0 = (l / NBlk) * 128;
    int n0 = (l % NBlk) * 128;
    int t = threadIdx.x;
    int w = t >> 6, ln = t & 63;
    int wm = (w >> 1) * 64, wn = (w & 1) * 64;

    const ushort_t* ag = A + (size_t)(m0 + w * 32 + (ln >> 2)) * K + (ln & 3) * 8;
    const ushort_t* bg = Bt + (size_t)(n0 + w * 32 + (ln >> 2)) * K + (ln & 3) * 8;

    f32x4 acc[4][4] = {};

    auto stage = [&](int buf, int k0) {
#pragma unroll
        for (int i = 0; i < 2; i++) {
            __builtin_amdgcn_global_load_lds(
                (gptr_t)(const void*)(ag + (size_t)i * 16 * K + k0),
                (lptr_t)(void*)(&sA[buf][(w * 32 + i * 16) * 32]), 16, 0, 0);
            __builtin_amdgcn_global_load_lds(
                (gptr_t)(const void*)(bg + (size_t)i * 16 * K + k0),
                (lptr_t)(void*)(&sB[buf][(w * 32 + i * 16) * 32]), 16, 0, 0);
        }
    };

    int nt = K >> 5;
    stage(0, 0);
    __syncthreads();
    int cur = 0;
    for (int tt = 0; tt < nt; tt++) {
        if (tt + 1 < nt) stage(cur ^ 1, (tt + 1) << 5);
        bf16x8 af[4], bfr[4];
#pragma unroll
        for (int m = 0; m < 4; m++)
            af[m] = *reinterpret_cast<const bf16x8*>(
                &sA[cur][(wm + m * 16 + (ln & 15)) * 32 + (ln >> 4) * 8]);
#pragma unroll
        for (int n = 0; n < 4; n++)
            bfr[n] = *reinterpret_cast<const bf16x8*>(
                &sB[cur][(wn + n * 16 + (ln & 15)) * 32 + (ln >> 4) * 8]);
#pragma unroll
        for (int m = 0; m < 4; m++)
#pragma unroll
            for (int n = 0; n < 4; n++)
                acc[m][n] = __builtin_amdgcn_mfma_f32_16x16x32_bf16(af[m], bfr[n], acc[m][n], 0, 0, 0);
        __syncthreads();
        cur ^= 1;
    }

    int cc = ln & 15, qq = ln >> 4;
#pragma unroll
    for (int m = 0; m < 4; m++) {
#pragma unroll
        for (int rr = 0; rr < 4; rr++) {
            int row = m0 + wm + m * 16 + qq * 4 + rr;
#pragma unroll
            for (int n = 0; n < 4; n++)
                C[(size_t)row * Nout + n0 + wn + n * 16 + cc] = f2bf(acc[m][n][rr]);
        }
    }

    float as_[4], ad_[4];
#pragma unroll
    for (int n = 0; n < 4; n++) {
        int col = n0 + wn + n * 16 + cc;
        as_[n] = att_s[col];
        ad_[n] = att_d[col];
    }
    __shared__ float sh_s[2][128];
    __shared__ float sh_d[2][128];
#pragma unroll
    for (int m = 0; m < 4; m++) {
#pragma unroll
        for (int rr = 0; rr < 4; rr++) {
            int rib = wm + m * 16 + qq * 4 + rr;
            float ps = acc[m][0][rr] * as_[0] + acc[m][1][rr] * as_[1] +
                       acc[m][2][rr] * as_[2] + acc[m][3][rr] * as_[3];
            float pd = acc[m][0][rr] * ad_[0] + acc[m][1][rr] * ad_[1] +
                       acc[m][2][rr] * ad_[2] + acc[m][3][rr] * ad_[3];
#pragma unroll
            for (int o = 1; o < 16; o <<= 1) {
                ps += __shfl_xor(ps, o, 64);
                pd += __shfl_xor(pd, o, 64);
            }
            if (cc == 0) {
                sh_s[wn >> 6][rib] = ps;
                sh_d[wn >> 6][rib] = pd;
            }
        }
    }
    __syncthreads();
    if (t < 128) {
        int row = m0 + t;
        if (row < N) {
            als[row] = sh_s[0][t] + sh_s[1][t];
            ald[row] = sh_d[0][t] + sh_d[1][t];
        }
    }
}

// -------- layer-1 agg: 4 nodes/block (4 indep waves), T14 issue-early gather --------
__global__ void __launch_bounds__(256) node_agg1(
    const ushort_t* __restrict__ h1b, const float* __restrict__ als, const float* __restrict__ ald,
    const float* __restrict__ rel_alpha, const int* __restrict__ rowptr,
    const int* __restrict__ src_pk,
    const float* __restrict__ b1, const float* __restrict__ g1, const float* __restrict__ beta1,
    ushort_t* __restrict__ out, int N) {
    __shared__ float sh_rel[NREL * NHEAD];
    if (threadIdx.x < NREL * NHEAD) sh_rel[threadIdx.x] = rel_alpha[threadIdx.x];
    __syncthreads();
    int l = threadIdx.x & 63;
    int i = blockIdx.x * 4 + (threadIdx.x >> 6);
    if (i >= N) return;
    int h = l & 7;
    int e8 = l >> 3;
    float als_i = als[i * NHEAD + h];
    float ald_h = ald[i * NHEAD + h];
    float c0, c1, c2, c3;
    {
        u16x4 v = *reinterpret_cast<const u16x4*>(h1b + (size_t)i * HID + 4 * l);
        c0 = b2f(v[0]); c1 = b2f(v[1]); c2 = b2f(v[2]); c3 = b2f(v[3]);
    }
    int base = rowptr[i];
    int deg = rowptr[i + 1] - base;
    const char* hb = reinterpret_cast<const char*>(h1b);
    float acc0 = 0.f, acc1 = 0.f, acc2 = 0.f, acc3 = 0.f;
    float csum = 0.f, rs = 0.f;
    for (int cs = 0; cs < deg; cs += 8) {
        int c = min(8, deg - cs);
        int pk = 0;
        if (e8 < c) pk = src_pk[base + cs + e8];
        unsigned offv = (unsigned)(pk & 0xFFFFFF) * (HID * 2);
        if (c == 8) {
            unsigned of[8];
            u16x4 v[8];
#pragma unroll
            for (int e = 0; e < 8; e++) of[e] = (unsigned)__shfl((int)offv, e * 8, 64);
#pragma unroll
            for (int e = 0; e < 8; e++)
                v[e] = *reinterpret_cast<const u16x4*>(hb + of[e] + 8 * l);
            int sv = pk & 0xFFFFFF;
            int tv = (unsigned)pk >> 24;
            float ra = sh_rel[tv * NHEAD + h];
            float w = __expf(fminf(leaky(als[sv * NHEAD + h] + ald_h + ra), 40.f));
            csum += w;
            rs += ra;
            float wt[8];
#pragma unroll
            for (int e = 0; e < 8; e++) wt[e] = __shfl(w, e * 8 + e8, 64);
#pragma unroll
            for (int e = 0; e < 8; e++) {
                acc0 += wt[e] * b2f(v[e][0]);
                acc1 += wt[e] * b2f(v[e][1]);
                acc2 += wt[e] * b2f(v[e][2]);
                acc3 += wt[e] * b2f(v[e][3]);
            }
        } else {
            float w = 0.f, ra = 0.f;
            if (e8 < c) {
                int sv = pk & 0xFFFFFF;
                int tv = (unsigned)pk >> 24;
                ra = sh_rel[tv * NHEAD + h];
                w = __expf(fminf(leaky(als[sv * NHEAD + h] + ald_h + ra), 40.f));
            }
            csum += w;
            rs += ra;
            for (int e = 0; e < c; e++) {
                float wt = __shfl(w, e * 8 + e8, 64);
                unsigned of = (unsigned)__shfl((int)offv, e * 8, 64);
                u16x4 v = *reinterpret_cast<const u16x4*>(hb + of + 8 * l);
                acc0 += wt * b2f(v[0]); acc1 += wt * b2f(v[1]);
                acc2 += wt * b2f(v[2]); acc3 += wt * b2f(v[3]);
            }
        }
    }
    for (int o = 8; o < 64; o <<= 1) {
        csum += __shfl_xor(csum, o, 64);
        rs += __shfl_xor(rs, o, 64);
    }
    float selfa = rs / fmaxf((float)deg, 1.0f);
    float wself = __expf(fminf(leaky(als_i + ald_h + selfa), 40.f));
    float stot = csum + wself;
    float s_g = __shfl(stot, e8, 64);
    float w_g = __shfl(wself, e8, 64);
    acc0 += w_g * c0; acc1 += w_g * c1; acc2 += w_g * c2; acc3 += w_g * c3;
    float inv = 1.0f / (s_g + 1e-16f);
    float4 bb = *reinterpret_cast<const float4*>(b1 + 4 * l);
    float y0 = acc0 * inv + bb.x, y1 = acc1 * inv + bb.y;
    float y2 = acc2 * inv + bb.z, y3 = acc3 * inv + bb.w;
    float su = y0 + y1 + y2 + y3;
    float sq = y0 * y0 + y1 * y1 + y2 * y2 + y3 * y3;
    for (int o = 1; o < 64; o <<= 1) {
        su += __shfl_xor(su, o, 64);
        sq += __shfl_xor(sq, o, 64);
    }
    float mean = su * (1.f / 256.f);
    float var = sq * (1.f / 256.f) - mean * mean;
    float rstd = rsqrtf(var + 1e-5f);
    float4 gg = *reinterpret_cast<const float4*>(g1 + 4 * l);
    float4 be = *reinterpret_cast<const float4*>(beta1 + 4 * l);
    float z0 = (y0 - mean) * rstd * gg.x + be.x;
    float z1 = (y1 - mean) * rstd * gg.y + be.y;
    float z2 = (y2 - mean) * rstd * gg.z + be.z;
    float z3 = (y3 - mean) * rstd * gg.w + be.w;
    u16x4 ov;
    ov[0] = f2bf(z0 > 0.f ? z0 : __expf(z0) - 1.f);
    ov[1] = f2bf(z1 > 0.f ? z1 : __expf(z1) - 1.f);
    ov[2] = f2bf(z2 > 0.f ? z2 : __expf(z2) - 1.f);
    ov[3] = f2bf(z3 > 0.f ? z3 : __expf(z3) - 1.f);
    *reinterpret_cast<u16x4*>(out + (size_t)i * HID + 4 * l) = ov;
}

// -------- layer-2 agg: 4 nodes/block, T14 issue-early on first 8-block --------
__global__ void __launch_bounds__(256) node_agg2(const ushort_t* __restrict__ h2b,
                                                 const float* __restrict__ als,
                                                 const float* __restrict__ ald,
                                                 const int* __restrict__ rowptr,
                                                 const int* __restrict__ src_pk,
                                                 const float* __restrict__ b2,
                                                 const float* __restrict__ g2,
                                                 const float* __restrict__ beta2,
                                                 float* __restrict__ out, int N) {
    int l = threadIdx.x & 63;
    int i = blockIdx.x * 4 + (threadIdx.x >> 6);
    if (i >= N) return;
    float aldi = ald[i];
    float alsi = als[i];
    float c0, c1;
    {
        u16x2 v = *reinterpret_cast<const u16x2*>(h2b + (size_t)i * OUT_DIM + 2 * l);
        c0 = b2f(v[0]); c1 = b2f(v[1]);
    }
    int base = rowptr[i];
    int deg = rowptr[i + 1] - base;
    const char* hb = reinterpret_cast<const char*>(h2b);
    float acc0 = 0.f, acc1 = 0.f;
    float csum = 0.f;
    for (int cs = 0; cs < deg; cs += 64) {
        int c = min(64, deg - cs);
        int pk = 0;
        if (l < c) pk = src_pk[base + cs + l];
        unsigned offv = (unsigned)(pk & 0xFFFFFF) * (OUT_DIM * 2);
        int e0 = 0;
        float w = 0.f;
        if (c >= 8) {
            unsigned of[8];
            u16x2 v[8];
#pragma unroll
            for (int jj = 0; jj < 8; jj++) of[jj] = (unsigned)__shfl((int)offv, jj, 64);
#pragma unroll
            for (int jj = 0; jj < 8; jj++)
                v[jj] = *reinterpret_cast<const u16x2*>(hb + of[jj] + 4 * l);
            if (l < c) w = __expf(fminf(leaky(als[pk & 0xFFFFFF] + aldi), 40.f));
            csum += w;
            float wt[8];
#pragma unroll
            for (int jj = 0; jj < 8; jj++) wt[jj] = __shfl(w, jj, 64);
#pragma unroll
            for (int jj = 0; jj < 8; jj++) {
                acc0 += wt[jj] * b2f(v[jj][0]);
                acc1 += wt[jj] * b2f(v[jj][1]);
            }
            e0 = 8;
        } else {
            if (l < c) w = __expf(fminf(leaky(als[pk & 0xFFFFFF] + aldi), 40.f));
            csum += w;
        }
        int e = e0;
        for (; e + 8 <= c; e += 8) {
            float wt[8];
            unsigned of[8];
            u16x2 v[8];
#pragma unroll
            for (int jj = 0; jj < 8; jj++) {
                wt[jj] = __shfl(w, e + jj, 64);
                of[jj] = (unsigned)__shfl((int)offv, e + jj, 64);
            }
#pragma unroll
            for (int jj = 0; jj < 8; jj++)
                v[jj] = *reinterpret_cast<const u16x2*>(hb + of[jj] + 4 * l);
#pragma unroll
            for (int jj = 0; jj < 8; jj++) {
                acc0 += wt[jj] * b2f(v[jj][0]);
                acc1 += wt[jj] * b2f(v[jj][1]);
            }
        }
        for (; e < c; e++) {
            float wt = __shfl(w, e, 64);
            unsigned of = (unsigned)__shfl((int)offv, e, 64);
            u16x2 v = *reinterpret_cast<const u16x2*>(hb + of + 4 * l);
            acc0 += wt * b2f(v[0]); acc1 += wt * b2f(v[1]);
        }
    }
    for (int o = 1; o < 64; o <<= 1) csum += __shfl_xor(csum, o, 64);
    float wself = __expf(fminf(leaky(alsi + aldi), 40.f));
    float s = csum + wself;
    acc0 += wself * c0; acc1 += wself * c1;
    float inv = 1.0f / (s + 1e-16f);
    float2 bb = *reinterpret_cast<const float2*>(b2 + 2 * l);
    float y0 = acc0 * inv + bb.x, y1 = acc1 * inv + bb.y;
    float su = y0 + y1, sq = y0 * y0 + y1 * y1;
    for (int o = 1; o < 64; o <<= 1) {
        su += __shfl_xor(su, o, 64);
        sq += __shfl_xor(sq, o, 64);
    }
    float mean = su * (1.f / 128.f);
    float var = sq * (1.f / 128.f) - mean * mean;
    float rstd = rsqrtf(var + 1e-5f);
    float2 gg = *reinterpret_cast<const float2*>(g2 + 2 * l);
    float2 be = *reinterpret_cast<const float2*>(beta2 + 2 * l);
    float2 ov;
    ov.x = (y0 - mean) * rstd * gg.x + be.x;
    ov.y = (y1 - mean) * rstd * gg.y + be.y;
    *reinterpret_cast<float2*>(out + (size_t)i * OUT_DIM + 2 * l) = ov;
}

extern "C" void kernel_launch(void* const* d_in, const int* in_sizes, int n_in,
                              void* d_out, int out_size, void* d_ws, size_t ws_size,
                              hipStream_t stream) {
    const float* x = (const float*)d_in[0];
    const int* ei = (const int*)d_in[1];
    const int* ety = (const int*)d_in[2];
    const float* rel_emb = (const float*)d_in[3];
    const float* W1 = (const float*)d_in[4];
    const float* att_s1 = (const float*)d_in[5];
    const float* att_d1 = (const float*)d_in[6];
    const float* We1 = (const float*)d_in[7];
    const float* att_e1 = (const float*)d_in[8];
    const float* b1 = (const float*)d_in[9];
    const float* g1 = (const float*)d_in[10];
    const float* beta1 = (const float*)d_in[11];
    const float* W2 = (const float*)d_in[12];
    const float* att_s2 = (const float*)d_in[13];
    const float* att_d2 = (const float*)d_in[14];
    const float* b2 = (const float*)d_in[15];
    const float* g2 = (const float*)d_in[16];
    const float* beta2 = (const float*)d_in[17];

    int N = in_sizes[0] / IN_DIM;
    int E = in_sizes[1] / 2;
    int Mpad = ((N + 127) / 128) * 128;
    const int* src0 = ei;
    const int* dst0 = ei + E;

    char* ws = (char*)d_ws;
    size_t off = 0;
    auto alloc = [&](size_t bytes) -> void* {
        off = (off + 255) & ~(size_t)255;
        void* p = ws + off;
        off += bytes;
        return p;
    };
    int* degfill = (int*)alloc((size_t)2 * N * 4);  // deg | fill, one memset
    int* deg = degfill;
    int* fill = degfill + N;
    int* rowptr = (int*)alloc((size_t)(N + 1) * 4);
    int* src_pk = (int*)alloc((size_t)E * 4);
    int nb = (N + 1023) >> 10;
    int* bsum = (int*)alloc((size_t)nb * 4);
    float* rel_alpha = (float*)alloc(NREL * NHEAD * 4);
    float* als1 = (float*)alloc((size_t)N * NHEAD * 4);
    float* ald1 = (float*)alloc((size_t)N * NHEAD * 4);
    float* al2s = (float*)alloc((size_t)N * 4);
    float* al2d = (float*)alloc((size_t)N * 4);
    ushort_t* W1t = (ushort_t*)alloc((size_t)HID * IN_DIM * 2);
    ushort_t* W2t = (ushort_t*)alloc((size_t)OUT_DIM * HID * 2);
    ushort_t* h1b = (ushort_t*)alloc((size_t)Mpad * HID * 2);
    ushort_t* h1pb = (ushort_t*)alloc((size_t)Mpad * HID * 2);
    ushort_t* h2b = h1b;  // h1b dead after node_agg1

    hipMemsetAsync(degfill, 0, (size_t)2 * N * 4, stream);

    int eb = (E + 255) / 256;
    count_kernel<<<eb, 256, 0, stream>>>(dst0, deg, E);
    scanA<<<nb, 256, 0, stream>>>(deg, bsum, N);
    scanC<<<nb, 256, 0, stream>>>(deg, bsum, rowptr, N, nb);
    scatter_kernel<<<eb, 256, 0, stream>>>(src0, dst0, ety, rowptr, fill, src_pk, E);
    int prep_elems = IN_DIM * HID + HID * OUT_DIM + NREL * NHEAD;
    prep_all<<<(prep_elems + 255) / 256, 256, 0, stream>>>(W1, W2, rel_emb, We1, att_e1,
                                                           W1t, W2t, rel_alpha);

    int NB1 = HID / 128;                 // 2 column blocks of 128
    int T1 = (Mpad / 64) * NB1;          // 64-row tiles
    gemm_f32a<<<T1, 256, 0, stream>>>(x, W1t, h1b, IN_DIM, HID, NB1,
                                      att_s1, att_d1, als1, ald1, N);
    node_agg1<<<(N + 3) / 4, 256, 0, stream>>>(h1b, als1, ald1, rel_alpha, rowptr, src_pk,
                                               b1, g1, beta1, h1pb, N);

    // h1pb rows [N, Mpad) contain stale bytes; gemm2 reads them in-bounds and the
    // resulting h2b rows >= N are never consumed -> no memset.
    int NB2 = OUT_DIM / 128;
    int T2 = (Mpad / 128) * NB2;
    gemm_lds2<<<T2, 256, 0, stream>>>(h1pb, W2t, h2b, HID, OUT_DIM, NB2,
                                      att_s2, att_d2, al2s, al2d, N);
    node_agg2<<<(N + 3) / 4, 256, 0, stream>>>(h2b, al2s, al2d, rowptr, src_pk, b2, g2, beta2,
                                               (float*)d_out, N);
}

// Round 19
// 322.585 us; speedup vs baseline: 1.0421x; 1.0421x over previous
//
#include <hip/hip_runtime.h>
#include <hip/hip_bf16.h>

#define IN_DIM 768
#define HID 256
#define OUT_DIM 128
#define NHEAD 8
#define NREL 6
#define RD 64

typedef unsigned short ushort_t;
typedef float f32x4 __attribute__((ext_vector_type(4)));
typedef __bf16 bf16x8 __attribute__((ext_vector_type(8)));
typedef unsigned short u16x8 __attribute__((ext_vector_type(8)));
typedef unsigned short u16x4 __attribute__((ext_vector_type(4)));
typedef unsigned short u16x2 __attribute__((ext_vector_type(2)));

typedef const __attribute__((address_space(1))) void* gptr_t;
typedef __attribute__((address_space(3))) void* lptr_t;

static __device__ __forceinline__ float leaky(float x) { return x > 0.f ? x : 0.2f * x; }

static __device__ __forceinline__ ushort_t f2bf(float f) {
    union { __hip_bfloat16 h; ushort_t u; } c;
    c.h = __float2bfloat16(f);
    return c.u;
}

static __device__ __forceinline__ float b2f(ushort_t u) {
    union { unsigned int i; float f; } c;
    c.i = ((unsigned int)u) << 16;
    return c.f;
}

// ---------------- CSR build ----------------
__global__ void count_kernel(const int* __restrict__ dst0, int* __restrict__ deg, int E) {
    int e = blockIdx.x * blockDim.x + threadIdx.x;
    if (e >= E) return;
    atomicAdd(&deg[dst0[e]], 1);
}

// per-1024-chunk sums
__global__ void __launch_bounds__(256) scanA(const int* __restrict__ deg,
                                             int* __restrict__ bsum, int n) {
    __shared__ int sh[4];
    int b = blockIdx.x, t = threadIdx.x;
    int s = 0;
#pragma unroll
    for (int j = 0; j < 4; j++) {
        int idx = b * 1024 + t * 4 + j;
        if (idx < n) s += deg[idx];
    }
    for (int o = 32; o > 0; o >>= 1) s += __shfl_xor(s, o, 64);
    if ((t & 63) == 0) sh[t >> 6] = s;
    __syncthreads();
    if (t == 0) bsum[b] = sh[0] + sh[1] + sh[2] + sh[3];
}

// expand: each block serially scans the <=nb chunk sums for its base
__global__ void __launch_bounds__(256) scanC(const int* __restrict__ deg,
                                             const int* __restrict__ bsum,
                                             int* __restrict__ rowptr, int n, int nb) {
    __shared__ int sh[256];
    int b = blockIdx.x, t = threadIdx.x;
    int bb = 0;
    for (int k = 0; k < b; k++) bb += bsum[k];
    if (b == 0 && t == 0) {
        int tot = 0;
        for (int k = 0; k < nb; k++) tot += bsum[k];
        rowptr[n] = tot;
    }
    int base = b * 1024;
    int loc[4];
    int run = 0;
#pragma unroll
    for (int j = 0; j < 4; j++) {
        int idx = base + t * 4 + j;
        int d = (idx < n) ? deg[idx] : 0;
        loc[j] = run;
        run += d;
    }
    int tot = run;
    sh[t] = run;
    __syncthreads();
    for (int o = 1; o < 256; o <<= 1) {
        int add = (t >= o) ? sh[t - o] : 0;
        __syncthreads();
        sh[t] += add;
        __syncthreads();
    }
    int texcl = sh[t] - tot;
#pragma unroll
    for (int j = 0; j < 4; j++) {
        int idx = base + t * 4 + j;
        if (idx < n) rowptr[idx] = bb + texcl + loc[j];
    }
}

// packs src | (type<<24) into one word
__global__ void scatter_kernel(const int* __restrict__ src0, const int* __restrict__ dst0,
                               const int* __restrict__ ety, const int* __restrict__ rowptr,
                               int* __restrict__ fill, int* __restrict__ src_pk, int E) {
    int e = blockIdx.x * blockDim.x + threadIdx.x;
    if (e >= E) return;
    int d = dst0[e];
    int pos = rowptr[d] + atomicAdd(&fill[d], 1);
    src_pk[pos] = src0[e] | (ety[e] << 24);
}

// W1 transpose+cvt, W2 transpose+cvt, and rel_alpha — ONE launch
__global__ void prep_all(const float* __restrict__ W1, const float* __restrict__ W2,
                         const float* __restrict__ rel_emb, const float* __restrict__ We1,
                         const float* __restrict__ att_e1,
                         ushort_t* __restrict__ W1t, ushort_t* __restrict__ W2t,
                         float* __restrict__ rel_alpha) {
    int i = blockIdx.x * 256 + threadIdx.x;
    if (i < IN_DIM * HID) {
        int k = i / HID, n = i % HID;
        W1t[n * IN_DIM + k] = f2bf(W1[i]);
    } else if (i < IN_DIM * HID + HID * OUT_DIM) {
        int j = i - IN_DIM * HID;
        int k = j / OUT_DIM, n = j % OUT_DIM;
        W2t[n * HID + k] = f2bf(W2[j]);
    } else {
        int t = i - (IN_DIM * HID + HID * OUT_DIM);
        if (t < NREL * NHEAD) {
            int r = t / NHEAD, h = t % NHEAD;
            float acc = 0.f;
            for (int c = 0; c < HID / NHEAD; c++) {
                float v = 0.f;
                for (int k = 0; k < RD; k++) v += rel_emb[r * RD + k] * We1[k * HID + h * 32 + c];
                acc += v * att_e1[h * 32 + c];
            }
            rel_alpha[r * NHEAD + h] = acc;
        }
    }
}

// ------- gemm1 (EXACT R17 config — empirical optimum): 64x128 tile, BK=64 single-buffer,
// A fp32 converted at fragment load. LDS 16K+16K=32KB -> 5 blocks/CU. Both-sides XOR chunk
// swizzle (A key=row&15 on 16x16B chunks, B key=row&7 on 8x16B chunks) -> 0 conflicts (R17).
__global__ void __launch_bounds__(256) gemm_f32a(const float* __restrict__ Af,
                                                 const ushort_t* __restrict__ Bt,
                                                 ushort_t* __restrict__ C,
                                                 int K, int Nout, int NBlk,
                                                 const float* __restrict__ att_s,
                                                 const float* __restrict__ att_d,
                                                 float* __restrict__ als,
                                                 float* __restrict__ ald, int N) {
    __shared__ float sAf[64 * 64];
    __shared__ ushort_t sB[128 * 64];
    int T = gridDim.x;
    int p = blockIdx.x;
    int q8 = T >> 3, rr8 = T & 7, xc = p & 7, jj0 = p >> 3;
    int l = (xc < rr8 ? xc * (q8 + 1) : rr8 * (q8 + 1) + (xc - rr8) * q8) + jj0;
    int m0 = (l / NBlk) * 64;
    int n0 = (l % NBlk) * 128;
    int t = threadIdx.x;
    int w = t >> 6, ln = t & 63;
    int wm = (w >> 1) * 32, wn = (w & 1) * 64;

    // A staging: 4 instr/wave; instr i: rows w*16+i*4+(ln>>4), chunk (ln&15)^(rl&15)
    const float* agp[4];
#pragma unroll
    for (int i = 0; i < 4; i++) {
        int rl = w * 16 + i * 4 + (ln >> 4);
        int rg = min(m0 + rl, N - 1);  // clamp: tail-row outputs never consumed
        int cc = (ln & 15) ^ (rl & 15);
        agp[i] = Af + (size_t)rg * K + (cc << 2);
    }
    // B staging: 4 instr/wave; rows w*32+i*8+(ln>>3), chunk (ln&7)^(ln>>3)
    const ushort_t* bgp[4];
#pragma unroll
    for (int i = 0; i < 4; i++) {
        int rl = w * 32 + i * 8 + (ln >> 3);
        int cc = (ln & 7) ^ (ln >> 3);  // rl&7 == ln>>3
        bgp[i] = Bt + (size_t)(n0 + rl) * K + (cc << 3);
    }

    f32x4 acc[2][4] = {};

    for (int k0 = 0; k0 < K; k0 += 64) {
#pragma unroll
        for (int i = 0; i < 4; i++)
            __builtin_amdgcn_global_load_lds((gptr_t)(const void*)(agp[i] + k0),
                                             (lptr_t)(void*)(&sAf[(w * 16 + i * 4) * 64]),
                                             16, 0, 0);
#pragma unroll
        for (int i = 0; i < 4; i++)
            __builtin_amdgcn_global_load_lds((gptr_t)(const void*)(bgp[i] + k0),
                                             (lptr_t)(void*)(&sB[(w * 32 + i * 8) * 64]),
                                             16, 0, 0);
        __syncthreads();
#pragma unroll
        for (int ks = 0; ks < 2; ks++) {
            bf16x8 af[2], bfr[4];
#pragma unroll
            for (int m = 0; m < 2; m++) {
                int r = wm + m * 16 + (ln & 15);
                int key = ln & 15;  // r & 15
                int c0 = ks * 8 + (ln >> 4) * 2;
                const f32x4* rowp = reinterpret_cast<const f32x4*>(&sAf[r * 64]);
                f32x4 lo = rowp[c0 ^ key];
                f32x4 hi = rowp[(c0 + 1) ^ key];
                union { u16x8 u; bf16x8 b; } cv;
                cv.u[0] = f2bf(lo[0]); cv.u[1] = f2bf(lo[1]);
                cv.u[2] = f2bf(lo[2]); cv.u[3] = f2bf(lo[3]);
                cv.u[4] = f2bf(hi[0]); cv.u[5] = f2bf(hi[1]);
                cv.u[6] = f2bf(hi[2]); cv.u[7] = f2bf(hi[3]);
                af[m] = cv.b;
            }
#pragma unroll
            for (int n = 0; n < 4; n++) {
                int r = wn + n * 16 + (ln & 15);
                int key = ln & 7;  // r & 7
                int cB = ks * 4 + (ln >> 4);
                bfr[n] = *reinterpret_cast<const bf16x8*>(&sB[r * 64 + ((cB ^ key) << 3)]);
            }
#pragma unroll
            for (int m = 0; m < 2; m++)
#pragma unroll
                for (int n = 0; n < 4; n++)
                    acc[m][n] = __builtin_amdgcn_mfma_f32_16x16x32_bf16(af[m], bfr[n], acc[m][n], 0, 0, 0);
        }
        __syncthreads();
    }

    int cc = ln & 15, qq = ln >> 4;
#pragma unroll
    for (int m = 0; m < 2; m++) {
#pragma unroll
        for (int rr = 0; rr < 4; rr++) {
            int row = m0 + wm + m * 16 + qq * 4 + rr;
#pragma unroll
            for (int n = 0; n < 4; n++)
                C[(size_t)row * Nout + n0 + wn + n * 16 + cc] = f2bf(acc[m][n][rr]);
        }
    }

    float as_[4], ad_[4];
#pragma unroll
    for (int n = 0; n < 4; n++) {
        int col = n0 + wn + n * 16 + cc;
        as_[n] = att_s[col];
        ad_[n] = att_d[col];
    }
    int hbase = (n0 + wn) >> 5;  // wave-exclusive head pair (rows split by w>>1)
#pragma unroll
    for (int m = 0; m < 2; m++) {
#pragma unroll
        for (int rr = 0; rr < 4; rr++) {
            int row = m0 + wm + m * 16 + qq * 4 + rr;
            float ps0 = acc[m][0][rr] * as_[0] + acc[m][1][rr] * as_[1];
            float ps1 = acc[m][2][rr] * as_[2] + acc[m][3][rr] * as_[3];
            float pd0 = acc[m][0][rr] * ad_[0] + acc[m][1][rr] * ad_[1];
            float pd1 = acc[m][2][rr] * ad_[2] + acc[m][3][rr] * ad_[3];
#pragma unroll
            for (int o = 1; o < 16; o <<= 1) {
                ps0 += __shfl_xor(ps0, o, 64);
                ps1 += __shfl_xor(ps1, o, 64);
                pd0 += __shfl_xor(pd0, o, 64);
                pd1 += __shfl_xor(pd1, o, 64);
            }
            if (cc == 0 && row < N) {
                als[row * NHEAD + hbase] = ps0;
                als[row * NHEAD + hbase + 1] = ps1;
                ald[row * NHEAD + hbase] = pd0;
                ald[row * NHEAD + hbase + 1] = pd1;
            }
        }
    }
}

// ------- gemm2 (bf16 A): BK=32 2-phase dbuf, AMODE-2 epilogue (unchanged) -------
__global__ void __launch_bounds__(256) gemm_lds2(const ushort_t* __restrict__ A,
                                                 const ushort_t* __restrict__ Bt,
                                                 ushort_t* __restrict__ C,
                                                 int K, int Nout, int NBlk,
                                                 const float* __restrict__ att_s,
                                                 const float* __restrict__ att_d,
                                                 float* __restrict__ als,
                                                 float* __restrict__ ald, int N) {
    __shared__ ushort_t sA[2][128 * 32];
    __shared__ ushort_t sB[2][128 * 32];
    int T = gridDim.x;
    int p = blockIdx.x;
    int q8 = T >> 3, rr8 = T & 7, xc = p & 7, j = p >> 3;
    int l = (xc < rr8 ? xc * (q8 + 1) : rr8 * (q8 + 1) + (xc - rr8) * q8) + j;
    int m0 = (l / NBlk) * 128;
    int n0 = (l % NBlk) * 128;
    int t = threadIdx.x;
    int w = t >> 6, ln = t & 63;
    int wm = (w >> 1) * 64, wn = (w & 1) * 64;

    const ushort_t* ag = A + (size_t)(m0 + w * 32 + (ln >> 2)) * K + (ln & 3) * 8;
    const ushort_t* bg = Bt + (size_t)(n0 + w * 32 + (ln >> 2)) * K + (ln & 3) * 8;

    f32x4 acc[4][4] = {};

    auto stage = [&](int buf, int k0) {
#pragma unroll
        for (int i = 0; i < 2; i++) {
            __builtin_amdgcn_global_load_lds(
                (gptr_t)(const void*)(ag + (size_t)i * 16 * K + k0),
                (lptr_t)(void*)(&sA[buf][(w * 32 + i * 16) * 32]), 16, 0, 0);
            __builtin_amdgcn_global_load_lds(
                (gptr_t)(const void*)(bg + (size_t)i * 16 * K + k0),
                (lptr_t)(void*)(&sB[buf][(w * 32 + i * 16) * 32]), 16, 0, 0);
        }
    };

    int nt = K >> 5;
    stage(0, 0);
    __syncthreads();
    int cur = 0;
    for (int tt = 0; tt < nt; tt++) {
        if (tt + 1 < nt) stage(cur ^ 1, (tt + 1) << 5);
        bf16x8 af[4], bfr[4];
#pragma unroll
        for (int m = 0; m < 4; m++)
            af[m] = *reinterpret_cast<const bf16x8*>(
                &sA[cur][(wm + m * 16 + (ln & 15)) * 32 + (ln >> 4) * 8]);
#pragma unroll
        for (int n = 0; n < 4; n++)
            bfr[n] = *reinterpret_cast<const bf16x8*>(
                &sB[cur][(wn + n * 16 + (ln & 15)) * 32 + (ln >> 4) * 8]);
#pragma unroll
        for (int m = 0; m < 4; m++)
#pragma unroll
            for (int n = 0; n < 4; n++)
                acc[m][n] = __builtin_amdgcn_mfma_f32_16x16x32_bf16(af[m], bfr[n], acc[m][n], 0, 0, 0);
        __syncthreads();
        cur ^= 1;
    }

    int cc = ln & 15, qq = ln >> 4;
#pragma unroll
    for (int m = 0; m < 4; m++) {
#pragma unroll
        for (int rr = 0; rr < 4; rr++) {
            int row = m0 + wm + m * 16 + qq * 4 + rr;
#pragma unroll
            for (int n = 0; n < 4; n++)
                C[(size_t)row * Nout + n0 + wn + n * 16 + cc] = f2bf(acc[m][n][rr]);
        }
    }

    float as_[4], ad_[4];
#pragma unroll
    for (int n = 0; n < 4; n++) {
        int col = n0 + wn + n * 16 + cc;
        as_[n] = att_s[col];
        ad_[n] = att_d[col];
    }
    __shared__ float sh_s[2][128];
    __shared__ float sh_d[2][128];
#pragma unroll
    for (int m = 0; m < 4; m++) {
#pragma unroll
        for (int rr = 0; rr < 4; rr++) {
            int rib = wm + m * 16 + qq * 4 + rr;
            float ps = acc[m][0][rr] * as_[0] + acc[m][1][rr] * as_[1] +
                       acc[m][2][rr] * as_[2] + acc[m][3][rr] * as_[3];
            float pd = acc[m][0][rr] * ad_[0] + acc[m][1][rr] * ad_[1] +
                       acc[m][2][rr] * ad_[2] + acc[m][3][rr] * ad_[3];
#pragma unroll
            for (int o = 1; o < 16; o <<= 1) {
                ps += __shfl_xor(ps, o, 64);
                pd += __shfl_xor(pd, o, 64);
            }
            if (cc == 0) {
                sh_s[wn >> 6][rib] = ps;
                sh_d[wn >> 6][rib] = pd;
            }
        }
    }
    __syncthreads();
    if (t < 128) {
        int row = m0 + t;
        if (row < N) {
            als[row] = sh_s[0][t] + sh_s[1][t];
            ald[row] = sh_d[0][t] + sh_d[1][t];
        }
    }
}

// -------- layer-1 agg: 4 nodes/block (4 indep waves), T14 issue-early gather --------
__global__ void __launch_bounds__(256) node_agg1(
    const ushort_t* __restrict__ h1b, const float* __restrict__ als, const float* __restrict__ ald,
    const float* __restrict__ rel_alpha, const int* __restrict__ rowptr,
    const int* __restrict__ src_pk,
    const float* __restrict__ b1, const float* __restrict__ g1, const float* __restrict__ beta1,
    ushort_t* __restrict__ out, int N) {
    __shared__ float sh_rel[NREL * NHEAD];
    if (threadIdx.x < NREL * NHEAD) sh_rel[threadIdx.x] = rel_alpha[threadIdx.x];
    __syncthreads();
    int l = threadIdx.x & 63;
    int i = blockIdx.x * 4 + (threadIdx.x >> 6);
    if (i >= N) return;
    int h = l & 7;
    int e8 = l >> 3;
    float als_i = als[i * NHEAD + h];
    float ald_h = ald[i * NHEAD + h];
    float c0, c1, c2, c3;
    {
        u16x4 v = *reinterpret_cast<const u16x4*>(h1b + (size_t)i * HID + 4 * l);
        c0 = b2f(v[0]); c1 = b2f(v[1]); c2 = b2f(v[2]); c3 = b2f(v[3]);
    }
    int base = rowptr[i];
    int deg = rowptr[i + 1] - base;
    const char* hb = reinterpret_cast<const char*>(h1b);
    float acc0 = 0.f, acc1 = 0.f, acc2 = 0.f, acc3 = 0.f;
    float csum = 0.f, rs = 0.f;
    for (int cs = 0; cs < deg; cs += 8) {
        int c = min(8, deg - cs);
        int pk = 0;
        if (e8 < c) pk = src_pk[base + cs + e8];
        unsigned offv = (unsigned)(pk & 0xFFFFFF) * (HID * 2);
        if (c == 8) {
            unsigned of[8];
            u16x4 v[8];
#pragma unroll
            for (int e = 0; e < 8; e++) of[e] = (unsigned)__shfl((int)offv, e * 8, 64);
#pragma unroll
            for (int e = 0; e < 8; e++)
                v[e] = *reinterpret_cast<const u16x4*>(hb + of[e] + 8 * l);
            int sv = pk & 0xFFFFFF;
            int tv = (unsigned)pk >> 24;
            float ra = sh_rel[tv * NHEAD + h];
            float w = __expf(fminf(leaky(als[sv * NHEAD + h] + ald_h + ra), 40.f));
            csum += w;
            rs += ra;
            float wt[8];
#pragma unroll
            for (int e = 0; e < 8; e++) wt[e] = __shfl(w, e * 8 + e8, 64);
#pragma unroll
            for (int e = 0; e < 8; e++) {
                acc0 += wt[e] * b2f(v[e][0]);
                acc1 += wt[e] * b2f(v[e][1]);
                acc2 += wt[e] * b2f(v[e][2]);
                acc3 += wt[e] * b2f(v[e][3]);
            }
        } else {
            float w = 0.f, ra = 0.f;
            if (e8 < c) {
                int sv = pk & 0xFFFFFF;
                int tv = (unsigned)pk >> 24;
                ra = sh_rel[tv * NHEAD + h];
                w = __expf(fminf(leaky(als[sv * NHEAD + h] + ald_h + ra), 40.f));
            }
            csum += w;
            rs += ra;
            for (int e = 0; e < c; e++) {
                float wt = __shfl(w, e * 8 + e8, 64);
                unsigned of = (unsigned)__shfl((int)offv, e * 8, 64);
                u16x4 v = *reinterpret_cast<const u16x4*>(hb + of + 8 * l);
                acc0 += wt * b2f(v[0]); acc1 += wt * b2f(v[1]);
                acc2 += wt * b2f(v[2]); acc3 += wt * b2f(v[3]);
            }
        }
    }
    for (int o = 8; o < 64; o <<= 1) {
        csum += __shfl_xor(csum, o, 64);
        rs += __shfl_xor(rs, o, 64);
    }
    float selfa = rs / fmaxf((float)deg, 1.0f);
    float wself = __expf(fminf(leaky(als_i + ald_h + selfa), 40.f));
    float stot = csum + wself;
    float s_g = __shfl(stot, e8, 64);
    float w_g = __shfl(wself, e8, 64);
    acc0 += w_g * c0; acc1 += w_g * c1; acc2 += w_g * c2; acc3 += w_g * c3;
    float inv = 1.0f / (s_g + 1e-16f);
    float4 bb = *reinterpret_cast<const float4*>(b1 + 4 * l);
    float y0 = acc0 * inv + bb.x, y1 = acc1 * inv + bb.y;
    float y2 = acc2 * inv + bb.z, y3 = acc3 * inv + bb.w;
    float su = y0 + y1 + y2 + y3;
    float sq = y0 * y0 + y1 * y1 + y2 * y2 + y3 * y3;
    for (int o = 1; o < 64; o <<= 1) {
        su += __shfl_xor(su, o, 64);
        sq += __shfl_xor(sq, o, 64);
    }
    float mean = su * (1.f / 256.f);
    float var = sq * (1.f / 256.f) - mean * mean;
    float rstd = rsqrtf(var + 1e-5f);
    float4 gg = *reinterpret_cast<const float4*>(g1 + 4 * l);
    float4 be = *reinterpret_cast<const float4*>(beta1 + 4 * l);
    float z0 = (y0 - mean) * rstd * gg.x + be.x;
    float z1 = (y1 - mean) * rstd * gg.y + be.y;
    float z2 = (y2 - mean) * rstd * gg.z + be.z;
    float z3 = (y3 - mean) * rstd * gg.w + be.w;
    u16x4 ov;
    ov[0] = f2bf(z0 > 0.f ? z0 : __expf(z0) - 1.f);
    ov[1] = f2bf(z1 > 0.f ? z1 : __expf(z1) - 1.f);
    ov[2] = f2bf(z2 > 0.f ? z2 : __expf(z2) - 1.f);
    ov[3] = f2bf(z3 > 0.f ? z3 : __expf(z3) - 1.f);
    *reinterpret_cast<u16x4*>(out + (size_t)i * HID + 4 * l) = ov;
}

// -------- layer-2 agg: 4 nodes/block, T14 issue-early on first 8-block --------
__global__ void __launch_bounds__(256) node_agg2(const ushort_t* __restrict__ h2b,
                                                 const float* __restrict__ als,
                                                 const float* __restrict__ ald,
                                                 const int* __restrict__ rowptr,
                                                 const int* __restrict__ src_pk,
                                                 const float* __restrict__ b2,
                                                 const float* __restrict__ g2,
                                                 const float* __restrict__ beta2,
                                                 float* __restrict__ out, int N) {
    int l = threadIdx.x & 63;
    int i = blockIdx.x * 4 + (threadIdx.x >> 6);
    if (i >= N) return;
    float aldi = ald[i];
    float alsi = als[i];
    float c0, c1;
    {
        u16x2 v = *reinterpret_cast<const u16x2*>(h2b + (size_t)i * OUT_DIM + 2 * l);
        c0 = b2f(v[0]); c1 = b2f(v[1]);
    }
    int base = rowptr[i];
    int deg = rowptr[i + 1] - base;
    const char* hb = reinterpret_cast<const char*>(h2b);
    float acc0 = 0.f, acc1 = 0.f;
    float csum = 0.f;
    for (int cs = 0; cs < deg; cs += 64) {
        int c = min(64, deg - cs);
        int pk = 0;
        if (l < c) pk = src_pk[base + cs + l];
        unsigned offv = (unsigned)(pk & 0xFFFFFF) * (OUT_DIM * 2);
        int e0 = 0;
        float w = 0.f;
        if (c >= 8) {
            unsigned of[8];
            u16x2 v[8];
#pragma unroll
            for (int jj = 0; jj < 8; jj++) of[jj] = (unsigned)__shfl((int)offv, jj, 64);
#pragma unroll
            for (int jj = 0; jj < 8; jj++)
                v[jj] = *reinterpret_cast<const u16x2*>(hb + of[jj] + 4 * l);
            if (l < c) w = __expf(fminf(leaky(als[pk & 0xFFFFFF] + aldi), 40.f));
            csum += w;
            float wt[8];
#pragma unroll
            for (int jj = 0; jj < 8; jj++) wt[jj] = __shfl(w, jj, 64);
#pragma unroll
            for (int jj = 0; jj < 8; jj++) {
                acc0 += wt[jj] * b2f(v[jj][0]);
                acc1 += wt[jj] * b2f(v[jj][1]);
            }
            e0 = 8;
        } else {
            if (l < c) w = __expf(fminf(leaky(als[pk & 0xFFFFFF] + aldi), 40.f));
            csum += w;
        }
        int e = e0;
        for (; e + 8 <= c; e += 8) {
            float wt[8];
            unsigned of[8];
            u16x2 v[8];
#pragma unroll
            for (int jj = 0; jj < 8; jj++) {
                wt[jj] = __shfl(w, e + jj, 64);
                of[jj] = (unsigned)__shfl((int)offv, e + jj, 64);
            }
#pragma unroll
            for (int jj = 0; jj < 8; jj++)
                v[jj] = *reinterpret_cast<const u16x2*>(hb + of[jj] + 4 * l);
#pragma unroll
            for (int jj = 0; jj < 8; jj++) {
                acc0 += wt[jj] * b2f(v[jj][0]);
                acc1 += wt[jj] * b2f(v[jj][1]);
            }
        }
        for (; e < c; e++) {
            float wt = __shfl(w, e, 64);
            unsigned of = (unsigned)__shfl((int)offv, e, 64);
            u16x2 v = *reinterpret_cast<const u16x2*>(hb + of + 4 * l);
            acc0 += wt * b2f(v[0]); acc1 += wt * b2f(v[1]);
        }
    }
    for (int o = 1; o < 64; o <<= 1) csum += __shfl_xor(csum, o, 64);
    float wself = __expf(fminf(leaky(alsi + aldi), 40.f));
    float s = csum + wself;
    acc0 += wself * c0; acc1 += wself * c1;
    float inv = 1.0f / (s + 1e-16f);
    float2 bb = *reinterpret_cast<const float2*>(b2 + 2 * l);
    float y0 = acc0 * inv + bb.x, y1 = acc1 * inv + bb.y;
    float su = y0 + y1, sq = y0 * y0 + y1 * y1;
    for (int o = 1; o < 64; o <<= 1) {
        su += __shfl_xor(su, o, 64);
        sq += __shfl_xor(sq, o, 64);
    }
    float mean = su * (1.f / 128.f);
    float var = sq * (1.f / 128.f) - mean * mean;
    float rstd = rsqrtf(var + 1e-5f);
    float2 gg = *reinterpret_cast<const float2*>(g2 + 2 * l);
    float2 be = *reinterpret_cast<const float2*>(beta2 + 2 * l);
    float2 ov;
    ov.x = (y0 - mean) * rstd * gg.x + be.x;
    ov.y = (y1 - mean) * rstd * gg.y + be.y;
    *reinterpret_cast<float2*>(out + (size_t)i * OUT_DIM + 2 * l) = ov;
}

extern "C" void kernel_launch(void* const* d_in, const int* in_sizes, int n_in,
                              void* d_out, int out_size, void* d_ws, size_t ws_size,
                              hipStream_t stream) {
    const float* x = (const float*)d_in[0];
    const int* ei = (const int*)d_in[1];
    const int* ety = (const int*)d_in[2];
    const float* rel_emb = (const float*)d_in[3];
    const float* W1 = (const float*)d_in[4];
    const float* att_s1 = (const float*)d_in[5];
    const float* att_d1 = (const float*)d_in[6];
    const float* We1 = (const float*)d_in[7];
    const float* att_e1 = (const float*)d_in[8];
    const float* b1 = (const float*)d_in[9];
    const float* g1 = (const float*)d_in[10];
    const float* beta1 = (const float*)d_in[11];
    const float* W2 = (const float*)d_in[12];
    const float* att_s2 = (const float*)d_in[13];
    const float* att_d2 = (const float*)d_in[14];
    const float* b2 = (const float*)d_in[15];
    const float* g2 = (const float*)d_in[16];
    const float* beta2 = (const float*)d_in[17];

    int N = in_sizes[0] / IN_DIM;
    int E = in_sizes[1] / 2;
    int Mpad = ((N + 127) / 128) * 128;
    const int* src0 = ei;
    const int* dst0 = ei + E;

    char* ws = (char*)d_ws;
    size_t off = 0;
    auto alloc = [&](size_t bytes) -> void* {
        off = (off + 255) & ~(size_t)255;
        void* p = ws + off;
        off += bytes;
        return p;
    };
    int* degfill = (int*)alloc((size_t)2 * N * 4);  // deg | fill, one memset
    int* deg = degfill;
    int* fill = degfill + N;
    int* rowptr = (int*)alloc((size_t)(N + 1) * 4);
    int* src_pk = (int*)alloc((size_t)E * 4);
    int nb = (N + 1023) >> 10;
    int* bsum = (int*)alloc((size_t)nb * 4);
    float* rel_alpha = (float*)alloc(NREL * NHEAD * 4);
    float* als1 = (float*)alloc((size_t)N * NHEAD * 4);
    float* ald1 = (float*)alloc((size_t)N * NHEAD * 4);
    float* al2s = (float*)alloc((size_t)N * 4);
    float* al2d = (float*)alloc((size_t)N * 4);
    ushort_t* W1t = (ushort_t*)alloc((size_t)HID * IN_DIM * 2);
    ushort_t* W2t = (ushort_t*)alloc((size_t)OUT_DIM * HID * 2);
    ushort_t* h1b = (ushort_t*)alloc((size_t)Mpad * HID * 2);
    ushort_t* h1pb = (ushort_t*)alloc((size_t)Mpad * HID * 2);
    ushort_t* h2b = h1b;  // h1b dead after node_agg1

    hipMemsetAsync(degfill, 0, (size_t)2 * N * 4, stream);

    int eb = (E + 255) / 256;
    count_kernel<<<eb, 256, 0, stream>>>(dst0, deg, E);
    scanA<<<nb, 256, 0, stream>>>(deg, bsum, N);
    scanC<<<nb, 256, 0, stream>>>(deg, bsum, rowptr, N, nb);
    scatter_kernel<<<eb, 256, 0, stream>>>(src0, dst0, ety, rowptr, fill, src_pk, E);
    int prep_elems = IN_DIM * HID + HID * OUT_DIM + NREL * NHEAD;
    prep_all<<<(prep_elems + 255) / 256, 256, 0, stream>>>(W1, W2, rel_emb, We1, att_e1,
                                                           W1t, W2t, rel_alpha);

    int NB1 = HID / 128;                 // 2 column blocks of 128
    int T1 = (Mpad / 64) * NB1;          // 64-row tiles
    gemm_f32a<<<T1, 256, 0, stream>>>(x, W1t, h1b, IN_DIM, HID, NB1,
                                      att_s1, att_d1, als1, ald1, N);
    node_agg1<<<(N + 3) / 4, 256, 0, stream>>>(h1b, als1, ald1, rel_alpha, rowptr, src_pk,
                                               b1, g1, beta1, h1pb, N);

    // h1pb rows [N, Mpad) contain stale bytes; gemm2 reads them in-bounds and the
    // resulting h2b rows >= N are never consumed -> no memset.
    int NB2 = OUT_DIM / 128;
    int T2 = (Mpad / 128) * NB2;
    gemm_lds2<<<T2, 256, 0, stream>>>(h1pb, W2t, h2b, HID, OUT_DIM, NB2,
                                      att_s2, att_d2, al2s, al2d, N);
    node_agg2<<<(N + 3) / 4, 256, 0, stream>>>(h2b, al2s, al2d, rowptr, src_pk, b2, g2, beta2,
                                               (float*)d_out, N);
}